// Round 11
// baseline (56.191 us; speedup 1.0000x reference)
//
#include <hip/hip_runtime.h>
#include <math.h>

#define NT 365
#define NT2 368
#define NS 128
#define NG 16
#define NH 8
#define HS 256
#define NSNH (NS * NH)
#define EPSC 1e-6f
#define TSTRIDE 96                  // floats per (site-group, t): 64 km + 8*float4 aux
#define TCH 46                      // t-chunk per scan wave (8 waves x 46 = 368)

// Workspace layout (floats):
//   prm: 6*NS*NH @ 0      order: gk, gl, qb, ga, gi, ge
//   Pf:  16*NT2*96 @ 8192     [64 km][8 x float4 {ps,pl,ev,0}] per (blk,t)
#define WS_PRM 0
#define WS_P   8192

__device__ __forceinline__ float fast_rcp(float v) {
#if __has_builtin(__builtin_amdgcn_rcpf)
    return __builtin_amdgcn_rcpf(v);
#else
    return 1.f / v;
#endif
}
__device__ __forceinline__ float fast_tanh(float xv) {
    float e = __expf(2.f * xv);   // overflow -> inf -> rcp -> 0 -> tanh=1 (correct limit)
    return 1.f - 2.f * fast_rcp(e + 1.f);
}
// acos(x)/pi for x in [-1,1], Hastings 4-term (abs err ~2.1e-5)
__device__ __forceinline__ float acos_over_pi(float r) {
    float ax = fabsf(r);
    float p = sqrtf(1.f - ax) *
              (0.49995890f + ax * (-0.06751697f + ax * (0.02363862f + ax * -0.00596153f)));
    return r < 0.f ? 1.f - p : p;
}

// ---------------- K_main: byte-identical to R10 ---------------------------
__global__ __launch_bounds__(256) void k_main(
    const float* __restrict__ x, const float* __restrict__ xc,
    const float* __restrict__ W_fc, const float* __restrict__ b_fc,
    const float* __restrict__ W_g, const float* __restrict__ b_g,
    const float* __restrict__ W_kin, const float* __restrict__ b_kin,
    const float* __restrict__ W_kout, const float* __restrict__ b_kout,
    float* __restrict__ prm, float* __restrict__ Pf)
{
    __shared__ float us[HS];                     // state + b_kin
    __shared__ float ts[HS];                     // tanh(state)
    __shared__ __align__(16) float4 wkin_lds[HS];
    __shared__ float wko_lds[8 * 260];           // padded rows
    __shared__ __align__(16) float lds_u[2 * 4 * 288];  // double-buffered
    __shared__ float pgs[6 * NH];

    int tid = threadIdx.x;
    int wave = tid >> 6, lane = tid & 63;
    int s = blockIdx.x & 127;
    int t0 = (blockIdx.x >> 7) * 4 + wave;       // 0..23
    int h = lane >> 3, jg = lane & 7;

    wkin_lds[tid] = ((const float4*)W_kin)[tid];
#pragma unroll
    for (int i = 0; i < 8; ++i) {
        int idx = tid + 256 * i;
        wko_lds[(idx >> 8) * 260 + (idx & 255)] = W_kout[idx];
    }
    {
        float a = b_fc[tid];
        const float4* wf = (const float4*)(W_fc + tid * NG);
        const float* xr = xc + s * NG;
#pragma unroll
        for (int i = 0; i < 4; ++i) {
            float4 w = wf[i];
            a += xr[4*i] * w.x + xr[4*i+1] * w.y + xr[4*i+2] * w.z + xr[4*i+3] * w.w;
        }
        ts[tid] = fast_tanh(a);
        us[tid] = a + b_kin[tid];
    }
    __syncthreads();

    float ust[4]; float4 w4[4];
#pragma unroll
    for (int r = 0; r < 4; ++r) {
        ust[r] = us[lane + 64 * r];
        w4[r]  = wkin_lds[lane + 64 * r];
    }
    float4 wwr[8];
#pragma unroll
    for (int k = 0; k < 8; ++k)
        wwr[k] = *(const float4*)(wko_lds + h * 260 + jg * 32 + 4 * k);
    float bko = b_kout[h];

    // fused param heads for blocks 0..127 (site == blockIdx)
    if (blockIdx.x < NS) {
        for (int k = wave; k < 6 * NH; k += 4) {
            float p = 0.f;
#pragma unroll
            for (int r = 0; r < 4; ++r) {
                int jj = lane + 64 * r;
                p += ts[jj] * W_g[k * HS + jj];
            }
#pragma unroll
            for (int off = 32; off; off >>= 1) p += __shfl_xor(p, off, 64);
            if (lane == 0) pgs[k] = p + b_g[k];
        }
        __syncthreads();
        if (tid < NH) {
            int hh = tid;
            float gk = expf(pgs[hh]) * 0.01f;
            float gl = expf(pgs[NH + hh]) * 100.f;
            float qb = fmaxf(pgs[2 * NH + hh], 0.f) * 0.1f;
            float m = pgs[3 * NH];
#pragma unroll
            for (int i = 1; i < NH; ++i) m = fmaxf(m, pgs[3 * NH + i]);
            float den = 0.f;
#pragma unroll
            for (int i = 0; i < NH; ++i) den += expf(pgs[3 * NH + i] - m);
            float ga = expf(pgs[3 * NH + hh] - m) / den;
            float gi = fminf(fmaxf(pgs[4 * NH + hh] * (1.f / 6.f) + 0.5f, 0.f), 1.f) * 0.5f;
            float ge = fmaxf(pgs[5 * NH + hh], 0.f);
            int o = s * NH + hh;
            prm[0 * NSNH + o] = gk;
            prm[1 * NSNH + o] = gl;
            prm[2 * NSNH + o] = qb;
            prm[3 * NSNH + o] = ga;
            prm[4 * NSNH + o] = gi;
            prm[5 * NSNH + o] = ge;
        }
    }

    int ubase = lane + 4 * (lane >> 5);          // u[j] at j + 4*(j>>5)
    int sblk = s >> 3, srem = (s & 7) * 8;

#pragma unroll 4
    for (int g = 0; g < 16; ++g) {
        int t = t0 + 24 * g;                     // 0..383
        if (t >= NT2) continue;                  // wave-uniform
        float* Pt = Pf + (size_t)(sblk * NT2 + t) * TSTRIDE;
        if (t >= NT) {                           // zero-pad 365..367
            if (jg == 0) Pt[srem + h] = 0.f;
            if (lane == 0)
                ((float4*)(Pt + 64))[s & 7] = make_float4(0.f, 0.f, 0.f, 0.f);
            continue;
        }
        float* uw = lds_u + ((g & 1) * 4 + wave) * 288;
        const float2* xr2 = (const float2*)(x + (size_t)(t * NS + s) * 6);
        float2 a01 = xr2[0], a23 = xr2[1], a45 = xr2[2];
        float prcp = a01.x, ev = a01.y;
        float f0 = a23.x, f1 = a23.y, f2 = a45.x, f3 = a45.y;
#pragma unroll
        for (int r = 0; r < 4; ++r) {
            float uval = fast_tanh(ust[r] + f0 * w4[r].x + f1 * w4[r].y +
                                   f2 * w4[r].z + f3 * w4[r].w);
            uw[ubase + 72 * r] = uval;
        }
        float r_ = (f0 + f1) * fast_rcp(fmaxf(f1 - f0, EPSC));
        r_ = fminf(fmaxf(r_, -1.f), 1.f);
        float vf = acos_over_pi(r_);
        if (f0 >= 0.f) vf = 0.f;
        if (f1 <= 0.f) vf = 1.f;
        float psv = prcp * vf;
        float plv = prcp * (1.f - vf);
        float acc = 0.f;
        const float4* uuP = (const float4*)(uw + jg * 36);
#pragma unroll
        for (int k = 0; k < 8; ++k) {
            float4 a = uuP[k], b = wwr[k];
            acc += a.x * b.x + a.y * b.y + a.z * b.z + a.w * b.w;
        }
        acc += __shfl_xor(acc, 1, 64);
        acc += __shfl_xor(acc, 2, 64);
        acc += __shfl_xor(acc, 4, 64);
        if (jg == 0) Pt[srem + h] = __expf(acc + bko);
        if (lane == 0)
            ((float4*)(Pt + 64))[s & 7] = make_float4(psv, plv, ev, 0.f);
    }
}

// ---------------- K_scan: byte-identical to R10 ---------------------------
__global__ __launch_bounds__(512, 1) void k_scan(
    const float* __restrict__ Pf, const float* __restrict__ prm,
    float* __restrict__ q)
{
    __shared__ float tup_sf[8][64][2];
    __shared__ __align__(16) float4 tup_S[8][64];
    __shared__ float region[8][64][17];

    int tid = threadIdx.x;
    int w = tid >> 6, lane = tid & 63;
    int blk = blockIdx.x;
    int sl = lane >> 3, ss0 = lane & 7;
    const float* Pb = Pf + (size_t)blk * (NT2 * TSTRIDE);
    int tbase = w * TCH;

    int gofs = blk * 64 + lane;
    float gk = prm[0 * NSNH + gofs];
    float gl = prm[1 * NSNH + gofs];
    float qb = prm[2 * NSNH + gofs];
    float gi = prm[4 * NSNH + gofs];
    float ge = prm[5 * NSNH + gofs];
    float c1 = 1.f - gk, nqb = -qb, nge = -ge;
    float hi = fmaxf(fmaf(gl, c1, nqb), 0.f);
    float gar[8];
#pragma unroll
    for (int hh = 0; hh < 8; ++hh)
        gar[hh] = prm[3 * NSNH + (blk * 8 + ss0) * 8 + hh];

    // ---- Phase A: compose sf-maps over the chunk ----
    float u = 0.f, v = 0.f;
#define PHA(BASE, COUNT) _Pragma("unroll") \
    for (int c = 0; c < COUNT; ++c) { \
        const float* Pt = Pb + (tbase + BASE + c) * TSTRIDE; \
        float km = Pt[lane]; \
        float ps = Pt[64 + 4 * sl]; \
        float d = ps - km; \
        u = u + d; \
        v = fmaxf(v + d, 0.f); \
    }
    PHA(0, 16) PHA(16, 16) PHA(32, 14)
#undef PHA
    tup_sf[w][lane][0] = u; tup_sf[w][lane][1] = v;
    __syncthreads();

    // sf prefix (w <= 7 scalar steps)
    float sfs = 0.f;
    for (int i = 0; i < w; ++i)
        sfs = fmaxf(sfs + tup_sf[i][lane][0], tup_sf[i][lane][1]);

    // ---- Phase B: replay sf, compose S-maps ----
    float aS = 1.f, bS = 0.f, lS = 0.f, hS = 1.0e30f;
    float sf = sfs;
#define PHB(BASE, COUNT) _Pragma("unroll") \
    for (int c = 0; c < COUNT; ++c) { \
        const float* Pt = Pb + (tbase + BASE + c) * TSTRIDE; \
        float km = Pt[lane]; \
        float4 a4 = ((const float4*)(Pt + 64))[sl]; \
        float sf1 = sf + a4.x; \
        float melt = fminf(sf1, km); \
        sf = sf1 - melt; \
        float b = fmaf(a4.z, nge, fmaf(a4.y, gi, melt)); \
        float beta = fmaf(b, c1, nqb); \
        aS = aS * c1; \
        bS = fmaf(bS, c1, beta); \
        lS = __builtin_amdgcn_fmed3f(fmaf(lS, c1, beta), 0.f, hi); \
        hS = __builtin_amdgcn_fmed3f(fmaf(hS, c1, beta), 0.f, hi); \
    }
    PHB(0, 16) PHB(16, 16) PHB(32, 14)
#undef PHB
    tup_S[w][lane] = make_float4(aS, bS, lS, hS);
    __syncthreads();

    // S prefix
    float Ss = 0.f;
    for (int i = 0; i < w; ++i) {
        float4 tp = tup_S[i][lane];
        Ss = __builtin_amdgcn_fmed3f(fmaf(Ss, tp.x, tp.y), tp.z, tp.w);
    }

    // ---- Phase C: serial replay with outputs + wave-private REDC ----
    float S = Ss;
    sf = sfs;
#define PHC(BASE, COUNT) { \
    _Pragma("unroll") for (int c = 0; c < 16; ++c) { \
        if (c < COUNT) { \
            const float* Pt = Pb + (tbase + BASE + c) * TSTRIDE; \
            float km = Pt[lane]; \
            float4 a4 = ((const float4*)(Pt + 64))[sl]; \
            float sf1 = sf + a4.x; \
            float melt = fminf(sf1, km); \
            sf = sf1 - melt; \
            float Sw = S + fmaf(a4.y, gi, melt); \
            float t2v = fmaf(a4.z, nge, Sw); \
            float S1 = fmaxf(t2v, 0.f); \
            float S2 = __builtin_amdgcn_fmed3f(t2v, 0.f, gl); \
            float Sn = fmaxf(fmaf(S2, c1, nqb), 0.f); \
            S = Sn; \
            region[w][lane][c] = S1 - Sn; \
        } \
    } \
    _Pragma("unroll") for (int it = 0; it < 2; ++it) { \
        int idx = it * 64 + lane; int cq = idx >> 3; \
        float sum = 0.f; \
        _Pragma("unroll") for (int hh = 0; hh < 8; ++hh) \
            sum = fmaf(gar[hh], region[w][ss0 * 8 + hh][cq], sum); \
        int t = tbase + BASE + cq; \
        if (cq < COUNT && t < NT) q[t * NS + blk * 8 + ss0] = sum; \
    } }
    PHC(0, 16) PHC(16, 16) PHC(32, 14)
#undef PHC
}

extern "C" void kernel_launch(void* const* d_in, const int* in_sizes, int n_in,
                              void* d_out, int out_size, void* d_ws, size_t ws_size,
                              hipStream_t stream)
{
    const float* x      = (const float*)d_in[0];
    const float* xc     = (const float*)d_in[1];
    const float* W_fc   = (const float*)d_in[2];
    const float* b_fc   = (const float*)d_in[3];
    const float* W_g    = (const float*)d_in[4];
    const float* b_g    = (const float*)d_in[5];
    const float* W_kin  = (const float*)d_in[6];
    const float* b_kin  = (const float*)d_in[7];
    const float* W_kout = (const float*)d_in[8];
    const float* b_kout = (const float*)d_in[9];
    float* q = (float*)d_out;

    float* ws  = (float*)d_ws;
    float* prm = ws + WS_PRM;
    float* Pf  = ws + WS_P;

    hipLaunchKernelGGL(k_main, dim3(768), dim3(256), 0, stream,
                       x, xc, W_fc, b_fc, W_g, b_g, W_kin, b_kin,
                       W_kout, b_kout, prm, Pf);

    // DIAGNOSTIC: k_scan launched 3x (idempotent — reads Pf/prm, overwrites
    // q with identical values). dur_R11 - dur_R10 = 2*(k_scan + node),
    // completing the decomposition started in R9 (k_main ~ 16 us there).
    for (int rep = 0; rep < 3; ++rep)
        hipLaunchKernelGGL(k_scan, dim3(16), dim3(512), 0, stream,
                           Pf, prm, q);
}

// Round 12
// 32.347 us; speedup vs baseline: 1.7371x; 1.7371x over previous
//
#include <hip/hip_runtime.h>
#include <math.h>

#define NT 365
#define NT2 368
#define NS 128
#define NG 16
#define NH 8
#define HS 256
#define NSNH (NS * NH)
#define EPSC 1e-6f
#define TSTRIDE 96                  // floats per (site-group, t): 64 km + 8*float4 aux
#define TCH 46                      // t-chunk per scan wave (8 waves x 46 = 368)

// Workspace layout (floats):
//   prm: 6*NS*NH @ 0      order: gk, gl, qb, ga, gi, ge
//   Pf:  16*NT2*96 @ 8192     [64 km][8 x float4 {ps,pl,ev,0}] per (blk,t)
#define WS_PRM 0
#define WS_P   8192

__device__ __forceinline__ float fast_rcp(float v) {
#if __has_builtin(__builtin_amdgcn_rcpf)
    return __builtin_amdgcn_rcpf(v);
#else
    return 1.f / v;
#endif
}
__device__ __forceinline__ float fast_tanh(float xv) {
    float e = __expf(2.f * xv);   // overflow -> inf -> rcp -> 0 -> tanh=1 (correct limit)
    return 1.f - 2.f * fast_rcp(e + 1.f);
}
// acos(x)/pi for x in [-1,1], Hastings 4-term (abs err ~2.1e-5)
__device__ __forceinline__ float acos_over_pi(float r) {
    float ax = fabsf(r);
    float p = sqrtf(1.f - ax) *
              (0.49995890f + ax * (-0.06751697f + ax * (0.02363862f + ax * -0.00596153f)));
    return r < 0.f ? 1.f - p : p;
}

// ---------------- K_main: byte-identical to R9 (1536-block structure) -----
__global__ __launch_bounds__(256) void k_main(
    const float* __restrict__ x, const float* __restrict__ xc,
    const float* __restrict__ W_fc, const float* __restrict__ b_fc,
    const float* __restrict__ W_g, const float* __restrict__ b_g,
    const float* __restrict__ W_kin, const float* __restrict__ b_kin,
    const float* __restrict__ W_kout, const float* __restrict__ b_kout,
    float* __restrict__ prm, float* __restrict__ Pf)
{
    __shared__ float us[HS];                     // state + b_kin
    __shared__ float ts[HS];                     // tanh(state)
    __shared__ __align__(16) float4 wkin_lds[HS];
    __shared__ float wko_lds[8 * 260];           // padded rows
    __shared__ __align__(16) float lds_u[4 * 288];
    __shared__ float pgs[6 * NH];

    int tid = threadIdx.x;
    int wave = tid >> 6, lane = tid & 63;
    int s = blockIdx.x & 127;
    int t0 = (blockIdx.x >> 7) * 4 + wave;       // 0..47
    int h = lane >> 3, jg = lane & 7;

    // stage W_kin (4KB) and W_kout (padded 8.3KB)
    wkin_lds[tid] = ((const float4*)W_kin)[tid];
#pragma unroll
    for (int i = 0; i < 8; ++i) {
        int idx = tid + 256 * i;
        wko_lds[(idx >> 8) * 260 + (idx & 255)] = W_kout[idx];
    }
    // state row tid for this block's site (one W_fc pass per block)
    {
        float a = b_fc[tid];
        const float4* wf = (const float4*)(W_fc + tid * NG);
        const float* xr = xc + s * NG;
#pragma unroll
        for (int i = 0; i < 4; ++i) {
            float4 w = wf[i];
            a += xr[4*i] * w.x + xr[4*i+1] * w.y + xr[4*i+2] * w.z + xr[4*i+3] * w.w;
        }
        ts[tid] = fast_tanh(a);
        us[tid] = a + b_kin[tid];
    }
    __syncthreads();

    // per-wave registers from LDS (read once, reused over 8 slots)
    float ust[4]; float4 w4[4];
#pragma unroll
    for (int r = 0; r < 4; ++r) {
        ust[r] = us[lane + 64 * r];
        w4[r]  = wkin_lds[lane + 64 * r];
    }
    float4 wwr[8];
#pragma unroll
    for (int k = 0; k < 8; ++k)
        wwr[k] = *(const float4*)(wko_lds + h * 260 + jg * 32 + 4 * k);
    float bko = b_kout[h];

    // fused param heads for blocks 0..127 (site == blockIdx)
    if (blockIdx.x < NS) {
        for (int k = wave; k < 6 * NH; k += 4) {
            float p = 0.f;
#pragma unroll
            for (int r = 0; r < 4; ++r) {
                int jj = lane + 64 * r;
                p += ts[jj] * W_g[k * HS + jj];
            }
#pragma unroll
            for (int off = 32; off; off >>= 1) p += __shfl_xor(p, off, 64);
            if (lane == 0) pgs[k] = p + b_g[k];
        }
        __syncthreads();
        if (tid < NH) {
            int hh = tid;
            float gk = expf(pgs[hh]) * 0.01f;
            float gl = expf(pgs[NH + hh]) * 100.f;
            float qb = fmaxf(pgs[2 * NH + hh], 0.f) * 0.1f;
            float m = pgs[3 * NH];
#pragma unroll
            for (int i = 1; i < NH; ++i) m = fmaxf(m, pgs[3 * NH + i]);
            float den = 0.f;
#pragma unroll
            for (int i = 0; i < NH; ++i) den += expf(pgs[3 * NH + i] - m);
            float ga = expf(pgs[3 * NH + hh] - m) / den;
            float gi = fminf(fmaxf(pgs[4 * NH + hh] * (1.f / 6.f) + 0.5f, 0.f), 1.f) * 0.5f;
            float ge = fmaxf(pgs[5 * NH + hh], 0.f);
            int o = s * NH + hh;
            prm[0 * NSNH + o] = gk;
            prm[1 * NSNH + o] = gl;
            prm[2 * NSNH + o] = qb;
            prm[3 * NSNH + o] = ga;
            prm[4 * NSNH + o] = gi;
            prm[5 * NSNH + o] = ge;
        }
    }

    // main forcing loop: 8 time slots per wave (R4/R8 structure)
    float* uw = lds_u + wave * 288;
    int ubase = lane + 4 * (lane >> 5);          // u[j] at j + 4*(j>>5)
    const float4* uuP = (const float4*)(uw + jg * 36);
    int sblk = s >> 3, srem = (s & 7) * 8;

#pragma unroll
    for (int g = 0; g < 8; ++g) {
        int t = t0 + 48 * g;                     // 0..383
        float* Pt = Pf + (size_t)(sblk * NT2 + t) * TSTRIDE;
        if (t >= NT) {                           // wave-uniform tail
            if (t < NT2) {
                if (jg == 0) Pt[srem + h] = 0.f;
                if (lane == 0)
                    ((float4*)(Pt + 64))[s & 7] = make_float4(0.f, 0.f, 0.f, 0.f);
            }
            continue;
        }
        const float2* xr2 = (const float2*)(x + (size_t)(t * NS + s) * 6);
        float2 a01 = xr2[0], a23 = xr2[1], a45 = xr2[2];
        float prcp = a01.x, ev = a01.y;
        float f0 = a23.x, f1 = a23.y, f2 = a45.x, f3 = a45.y;
#pragma unroll
        for (int r = 0; r < 4; ++r) {
            float uval = fast_tanh(ust[r] + f0 * w4[r].x + f1 * w4[r].y +
                                   f2 * w4[r].z + f3 * w4[r].w);
            uw[ubase + 72 * r] = uval;
        }
        float r_ = (f0 + f1) * fast_rcp(fmaxf(f1 - f0, EPSC));
        r_ = fminf(fmaxf(r_, -1.f), 1.f);
        float vf = acos_over_pi(r_);
        if (f0 >= 0.f) vf = 0.f;
        if (f1 <= 0.f) vf = 1.f;
        float psv = prcp * vf;
        float plv = prcp * (1.f - vf);
        float acc = 0.f;
#pragma unroll
        for (int k = 0; k < 8; ++k) {
            float4 a = uuP[k], b = wwr[k];
            acc += a.x * b.x + a.y * b.y + a.z * b.z + a.w * b.w;
        }
        acc += __shfl_xor(acc, 1, 64);
        acc += __shfl_xor(acc, 2, 64);
        acc += __shfl_xor(acc, 4, 64);
        if (jg == 0) Pt[srem + h] = __expf(acc + bko);
        if (lane == 0)
            ((float4*)(Pt + 64))[s & 7] = make_float4(psv, plv, ev, 0.f);
    }
}

// ---------------- K_scan: byte-identical to R10 ---------------------------
__global__ __launch_bounds__(512, 1) void k_scan(
    const float* __restrict__ Pf, const float* __restrict__ prm,
    float* __restrict__ q)
{
    __shared__ float tup_sf[8][64][2];
    __shared__ __align__(16) float4 tup_S[8][64];
    __shared__ float region[8][64][17];

    int tid = threadIdx.x;
    int w = tid >> 6, lane = tid & 63;
    int blk = blockIdx.x;
    int sl = lane >> 3, ss0 = lane & 7;
    const float* Pb = Pf + (size_t)blk * (NT2 * TSTRIDE);
    int tbase = w * TCH;

    int gofs = blk * 64 + lane;
    float gk = prm[0 * NSNH + gofs];
    float gl = prm[1 * NSNH + gofs];
    float qb = prm[2 * NSNH + gofs];
    float gi = prm[4 * NSNH + gofs];
    float ge = prm[5 * NSNH + gofs];
    float c1 = 1.f - gk, nqb = -qb, nge = -ge;
    float hi = fmaxf(fmaf(gl, c1, nqb), 0.f);
    float gar[8];
#pragma unroll
    for (int hh = 0; hh < 8; ++hh)
        gar[hh] = prm[3 * NSNH + (blk * 8 + ss0) * 8 + hh];

    // ---- Phase A: compose sf-maps over the chunk ----
    float u = 0.f, v = 0.f;
#define PHA(BASE, COUNT) _Pragma("unroll") \
    for (int c = 0; c < COUNT; ++c) { \
        const float* Pt = Pb + (tbase + BASE + c) * TSTRIDE; \
        float km = Pt[lane]; \
        float ps = Pt[64 + 4 * sl]; \
        float d = ps - km; \
        u = u + d; \
        v = fmaxf(v + d, 0.f); \
    }
    PHA(0, 16) PHA(16, 16) PHA(32, 14)
#undef PHA
    tup_sf[w][lane][0] = u; tup_sf[w][lane][1] = v;
    __syncthreads();

    // sf prefix (w <= 7 scalar steps)
    float sfs = 0.f;
    for (int i = 0; i < w; ++i)
        sfs = fmaxf(sfs + tup_sf[i][lane][0], tup_sf[i][lane][1]);

    // ---- Phase B: replay sf, compose S-maps ----
    float aS = 1.f, bS = 0.f, lS = 0.f, hS = 1.0e30f;
    float sf = sfs;
#define PHB(BASE, COUNT) _Pragma("unroll") \
    for (int c = 0; c < COUNT; ++c) { \
        const float* Pt = Pb + (tbase + BASE + c) * TSTRIDE; \
        float km = Pt[lane]; \
        float4 a4 = ((const float4*)(Pt + 64))[sl]; \
        float sf1 = sf + a4.x; \
        float melt = fminf(sf1, km); \
        sf = sf1 - melt; \
        float b = fmaf(a4.z, nge, fmaf(a4.y, gi, melt)); \
        float beta = fmaf(b, c1, nqb); \
        aS = aS * c1; \
        bS = fmaf(bS, c1, beta); \
        lS = __builtin_amdgcn_fmed3f(fmaf(lS, c1, beta), 0.f, hi); \
        hS = __builtin_amdgcn_fmed3f(fmaf(hS, c1, beta), 0.f, hi); \
    }
    PHB(0, 16) PHB(16, 16) PHB(32, 14)
#undef PHB
    tup_S[w][lane] = make_float4(aS, bS, lS, hS);
    __syncthreads();

    // S prefix
    float Ss = 0.f;
    for (int i = 0; i < w; ++i) {
        float4 tp = tup_S[i][lane];
        Ss = __builtin_amdgcn_fmed3f(fmaf(Ss, tp.x, tp.y), tp.z, tp.w);
    }

    // ---- Phase C: serial replay with outputs + wave-private REDC ----
    float S = Ss;
    sf = sfs;
#define PHC(BASE, COUNT) { \
    _Pragma("unroll") for (int c = 0; c < 16; ++c) { \
        if (c < COUNT) { \
            const float* Pt = Pb + (tbase + BASE + c) * TSTRIDE; \
            float km = Pt[lane]; \
            float4 a4 = ((const float4*)(Pt + 64))[sl]; \
            float sf1 = sf + a4.x; \
            float melt = fminf(sf1, km); \
            sf = sf1 - melt; \
            float Sw = S + fmaf(a4.y, gi, melt); \
            float t2v = fmaf(a4.z, nge, Sw); \
            float S1 = fmaxf(t2v, 0.f); \
            float S2 = __builtin_amdgcn_fmed3f(t2v, 0.f, gl); \
            float Sn = fmaxf(fmaf(S2, c1, nqb), 0.f); \
            S = Sn; \
            region[w][lane][c] = S1 - Sn; \
        } \
    } \
    _Pragma("unroll") for (int it = 0; it < 2; ++it) { \
        int idx = it * 64 + lane; int cq = idx >> 3; \
        float sum = 0.f; \
        _Pragma("unroll") for (int hh = 0; hh < 8; ++hh) \
            sum = fmaf(gar[hh], region[w][ss0 * 8 + hh][cq], sum); \
        int t = tbase + BASE + cq; \
        if (cq < COUNT && t < NT) q[t * NS + blk * 8 + ss0] = sum; \
    } }
    PHC(0, 16) PHC(16, 16) PHC(32, 14)
#undef PHC
}

extern "C" void kernel_launch(void* const* d_in, const int* in_sizes, int n_in,
                              void* d_out, int out_size, void* d_ws, size_t ws_size,
                              hipStream_t stream)
{
    const float* x      = (const float*)d_in[0];
    const float* xc     = (const float*)d_in[1];
    const float* W_fc   = (const float*)d_in[2];
    const float* b_fc   = (const float*)d_in[3];
    const float* W_g    = (const float*)d_in[4];
    const float* b_g    = (const float*)d_in[5];
    const float* W_kin  = (const float*)d_in[6];
    const float* b_kin  = (const float*)d_in[7];
    const float* W_kout = (const float*)d_in[8];
    const float* b_kout = (const float*)d_in[9];
    float* q = (float*)d_out;

    float* ws  = (float*)d_ws;
    float* prm = ws + WS_PRM;
    float* Pf  = ws + WS_P;

    hipLaunchKernelGGL(k_main, dim3(1536), dim3(256), 0, stream,
                       x, xc, W_fc, b_fc, W_g, b_g, W_kin, b_kin,
                       W_kout, b_kout, prm, Pf);

    hipLaunchKernelGGL(k_scan, dim3(16), dim3(512), 0, stream,
                       Pf, prm, q);
}